// Round 6
// baseline (544.022 us; speedup 1.0000x reference)
//
#include <hip/hip_runtime.h>
#include <math.h>

#define DIMC 512
#define EC   336
#define E3   1008
#define HDC  56
#define BB   8
#define LL   4096
#define NN   32768
#define KC   819
#define KCP  832        // padded per-batch token stride (multiple of 32)
#define YTS  (BB*KCP)   // 6656: Yt row stride (per channel); also padded G3 M
#define TRUNC 160   // effective taps: |K2[m]| ~ rho^m, rho<~0.5 => tail < 1e-40 at 160

// padded dims for the MFMA GEMMs (zero-padded => bit-identical results)
#define KP2  352    // K: 336 -> 352 (multiple of 32) for GEMM2/GEMM3
#define NP1  384    // B-rows for GEMM1: 336 -> 384 (multiple of 128)
#define NP2  1024   // B-rows for GEMM2: 1008 -> 1024 (multiple of 128)

typedef short bf16x8 __attribute__((ext_vector_type(8)));
typedef float f32x4 __attribute__((ext_vector_type(4)));

__device__ __forceinline__ float sigmoidf_(float x){ return 1.f/(1.f+expf(-x)); }
__device__ __forceinline__ unsigned short bf16rn_(float x){
  unsigned u = __float_as_uint(x);
  unsigned r = (u + 0x7FFFu + ((u>>16)&1u)) >> 16;
  return (unsigned short)r;
}
__device__ __forceinline__ float bf2f_(unsigned short h){ return __uint_as_float(((unsigned)h)<<16); }

// 3-way split: x ~= p0 + p1 + p2, residual ~2^-27 relative
__device__ __forceinline__ void split3_(float v, unsigned short& p0, unsigned short& p1, unsigned short& p2){
  p0 = bf16rn_(v);           float r1 = v - bf2f_(p0);
  p1 = bf16rn_(r1);          float r2 = r1 - bf2f_(p1);
  p2 = bf16rn_(r2);
}

#define GLDS(g, l) __builtin_amdgcn_global_load_lds( \
    (const __attribute__((address_space(1))) unsigned int*)(g), \
    (__attribute__((address_space(3))) unsigned int*)(l), 16, 0, 0)

// ---------- weight prep: W_in and W_qkv -> 3 bf16 planes, PADDED [Np][Kp] ----------
__global__ __launch_bounds__(256) void prepw3x2_k(const float* __restrict__ Wa,
    unsigned short* __restrict__ A0, unsigned short* __restrict__ A1, unsigned short* __restrict__ A2,
    const float* __restrict__ Wb,
    unsigned short* __restrict__ B0, unsigned short* __restrict__ B1, unsigned short* __restrict__ B2) {
  int i = blockIdx.x*256 + threadIdx.x;
  const int na = NP1*DIMC;     // W_in^T padded: [384][512]
  const int nb = NP2*KP2;      // W_qkv^T padded: [1024][352]
  if (i < na) {
    int n = i >> 9, k = i & 511;
    float w = (n < EC) ? Wa[(size_t)k*EC + n] : 0.f;
    unsigned short a,b,c; split3_(w, a, b, c);
    A0[i] = a; A1[i] = b; A2[i] = c;
  } else {
    int i2 = i - na;
    if (i2 < nb) {
      int n = i2 / KP2, k = i2 - n*KP2;
      float w = (n < E3 && k < EC) ? Wb[(size_t)k*E3 + n] : 0.f;
      unsigned short a,b,c; split3_(w, a, b, c);
      B0[i2] = a; B1[i2] = b; B2[i2] = c;
    }
  }
}
// 2-plane variant for W_out, PADDED [512][352]
__global__ __launch_bounds__(256) void prepwo_k(const float* __restrict__ W,
                        unsigned short* __restrict__ Th, unsigned short* __restrict__ Tl) {
  int i = blockIdx.x*256 + threadIdx.x;
  if (i >= DIMC*KP2) return;
  int n = i / KP2, k = i - n*KP2;
  float w = (k < EC) ? W[(size_t)k*DIMC + n] : 0.f;
  unsigned short h = bf16rn_(w);
  Th[i] = h;
  Tl[i] = bf16rn_(w - bf2f_(h));
}

// ---------- 1. DyT (full batch): xn = tanh(alpha*x)*w + b -> 3 bf16 planes ----------
__global__ __launch_bounds__(256) void dyt_k(const float* __restrict__ x, unsigned short* __restrict__ x0,
                      unsigned short* __restrict__ x1, unsigned short* __restrict__ x2,
                      const float* __restrict__ alpha, const float* __restrict__ dw,
                      const float* __restrict__ db) {
  size_t i = (size_t)blockIdx.x*256 + threadIdx.x;   // float4 index over NN*512/4
  int c = ((int)(i & 127)) << 2;
  float a = alpha[0];
  float4 v = ((const float4*)x)[i];
  float o[4];
  o[0] = tanhf(a*v.x)*dw[c+0]+db[c+0];
  o[1] = tanhf(a*v.y)*dw[c+1]+db[c+1];
  o[2] = tanhf(a*v.z)*dw[c+2]+db[c+2];
  o[3] = tanhf(a*v.w)*dw[c+3]+db[c+3];
  ushort4 a0, a1, a2;
  split3_(o[0], a0.x, a1.x, a2.x);
  split3_(o[1], a0.y, a1.y, a2.y);
  split3_(o[2], a0.z, a1.z, a2.z);
  split3_(o[3], a0.w, a1.w, a2.w);
  ((ushort4*)x0)[i] = a0;
  ((ushort4*)x1)[i] = a1;
  ((ushort4*)x2)[i] = a2;
}

// ---------- MFMA fp32-emulated GEMM: 3 bf16 planes each side, 6 terms ----------
// A: global_load_lds staged, DOUBLE-BUFFERED linear LDS (chunk-XOR swizzled src+read).
// B: L2-resident weight panel -> fragments loaded DIRECTLY global->regs (no LDS).
// One barrier per k-step; next-tile A prefetch issued before compute (T3/T4 pattern):
// B-frag loads issued FIRST so the compiler's counted vmcnt for them leaves the
// 6 prefetch GLDS (issued after, retire later) in flight across the MFMA phase.
__global__ __launch_bounds__(256,3) void mgemm6_k(const unsigned short* __restrict__ A0,
    const unsigned short* __restrict__ A1, const unsigned short* __restrict__ A2,
    const unsigned short* __restrict__ B0, const unsigned short* __restrict__ B1,
    const unsigned short* __restrict__ B2, const float* __restrict__ bias,
    float* __restrict__ C, int N, int Kp) {
  __shared__ unsigned short sA0[2][4096], sA1[2][4096], sA2[2][4096];
  int t = threadIdx.x;
  int nwg = gridDim.x*gridDim.y;          // 768 (G1) / 2048 (G2): % 8 == 0
  int bid = blockIdx.y*gridDim.x + blockIdx.x;
  int cpx = nwg >> 3;
  int swz = (bid & 7)*cpx + (bid >> 3);
  int by = swz / gridDim.x;
  int bx = swz - by*gridDim.x;
  int m0 = by*128, n0 = bx*128;
  int wave = t >> 6, lane = t & 63;
  int wm = (wave & 1)*64, wn = (wave >> 1)*64;
  int l15 = lane & 15, quad = lane >> 4;
  int srow = wave*32 + (lane >> 2);
  int sko  = ((lane & 3) ^ ((lane >> 3) & 3)) * 8;   // chunk-XOR pre-swizzled source
  const unsigned short* ga0 = A0 + (size_t)(m0 + srow)*Kp + sko;
  const unsigned short* ga1 = A1 + (size_t)(m0 + srow)*Kp + sko;
  const unsigned short* ga2 = A2 + (size_t)(m0 + srow)*Kp + sko;
  int seg2 = 16*Kp;
  int lws = wave*1024;
  // B fragment global base: row n0+wn+l15, col quad*8 (+ j*16*Kp + k0 in-loop)
  const unsigned short* pb0 = B0 + (size_t)(n0 + wn + l15)*Kp + quad*8;
  const unsigned short* pb1 = B1 + (size_t)(n0 + wn + l15)*Kp + quad*8;
  const unsigned short* pb2 = B2 + (size_t)(n0 + wn + l15)*Kp + quad*8;
  // prologue: stage tile 0 into buffer 0
  GLDS(ga0, &sA0[0][lws]);  GLDS(ga0 + seg2, &sA0[0][lws + 512]);
  GLDS(ga1, &sA1[0][lws]);  GLDS(ga1 + seg2, &sA1[0][lws + 512]);
  GLDS(ga2, &sA2[0][lws]);  GLDS(ga2 + seg2, &sA2[0][lws + 512]);
  f32x4 acc[4][4] = {};
  int nk = Kp >> 5;
  int kq = (quad ^ ((l15 >> 1) & 3)) * 8;             // swizzled read chunk
  for (int tt = 0; tt < nk; ++tt) {
    int k0 = tt << 5;
    int cur = tt & 1;
    __syncthreads();      // drains buf[cur]'s GLDS (overlapped with previous MFMA)
    // B fragments first (counted vmcnt will wait these, not the prefetch)
    bf16x8 fb0[4], fb1[4], fb2[4];
    #pragma unroll
    for (int j = 0; j < 4; ++j) {
      size_t off = (size_t)(j*16)*Kp + k0;
      fb0[j] = *(const bf16x8*)(pb0 + off);
      fb1[j] = *(const bf16x8*)(pb1 + off);
      fb2[j] = *(const bf16x8*)(pb2 + off);
    }
    if (tt + 1 < nk) {    // prefetch next A tile into other buffer
      int nxt = cur ^ 1;
      GLDS(ga0 + k0+32, &sA0[nxt][lws]);  GLDS(ga0 + k0+32 + seg2, &sA0[nxt][lws + 512]);
      GLDS(ga1 + k0+32, &sA1[nxt][lws]);  GLDS(ga1 + k0+32 + seg2, &sA1[nxt][lws + 512]);
      GLDS(ga2 + k0+32, &sA2[nxt][lws]);  GLDS(ga2 + k0+32 + seg2, &sA2[nxt][lws + 512]);
    }
    bf16x8 fa0[4], fa1[4], fa2[4];
    #pragma unroll
    for (int i = 0; i < 4; ++i) {
      int ra = (wm + i*16 + l15)*32 + kq;
      fa0[i] = *(const bf16x8*)&sA0[cur][ra];
      fa1[i] = *(const bf16x8*)&sA1[cur][ra];
      fa2[i] = *(const bf16x8*)&sA2[cur][ra];
    }
    #pragma unroll
    for (int i = 0; i < 4; ++i)
      #pragma unroll
      for (int j = 0; j < 4; ++j) {
        acc[i][j] = __builtin_amdgcn_mfma_f32_16x16x32_bf16(fa1[i], fb1[j], acc[i][j], 0, 0, 0);
        acc[i][j] = __builtin_amdgcn_mfma_f32_16x16x32_bf16(fa0[i], fb2[j], acc[i][j], 0, 0, 0);
        acc[i][j] = __builtin_amdgcn_mfma_f32_16x16x32_bf16(fa2[i], fb0[j], acc[i][j], 0, 0, 0);
        acc[i][j] = __builtin_amdgcn_mfma_f32_16x16x32_bf16(fa0[i], fb1[j], acc[i][j], 0, 0, 0);
        acc[i][j] = __builtin_amdgcn_mfma_f32_16x16x32_bf16(fa1[i], fb0[j], acc[i][j], 0, 0, 0);
        acc[i][j] = __builtin_amdgcn_mfma_f32_16x16x32_bf16(fa0[i], fb0[j], acc[i][j], 0, 0, 0);
      }
  }
  #pragma unroll
  for (int i = 0; i < 4; ++i) {
    #pragma unroll
    for (int j = 0; j < 4; ++j) {
      int col = n0 + wn + j*16 + l15;
      if (col >= N) continue;
      float bv = bias[col];
      #pragma unroll
      for (int r = 0; r < 4; ++r) {
        int row = m0 + wm + i*16 + quad*4 + r;
        C[(size_t)row*N + col] = acc[i][j][r] + bv;
      }
    }
  }
}

// ---------- MFMA bf16x3 GEMM (2 planes, 3 terms), same dbuf+direct-B — GEMM3 ----------
__global__ __launch_bounds__(256,2) void mgemm3_k(const unsigned short* __restrict__ Ah,
    const unsigned short* __restrict__ Al, const unsigned short* __restrict__ Bh,
    const unsigned short* __restrict__ Bl, const float* __restrict__ bias,
    float* __restrict__ C, int N, int Kp) {
  __shared__ unsigned short sAh[2][4096], sAl[2][4096];
  int t = threadIdx.x;
  int nwg = gridDim.x*gridDim.y;          // 208: % 8 == 0
  int bid = blockIdx.y*gridDim.x + blockIdx.x;
  int cpx = nwg >> 3;
  int swz = (bid & 7)*cpx + (bid >> 3);
  int by = swz / gridDim.x;
  int bx = swz - by*gridDim.x;
  int m0 = by*128, n0 = bx*128;
  int wave = t >> 6, lane = t & 63;
  int wm = (wave & 1)*64, wn = (wave >> 1)*64;
  int l15 = lane & 15, quad = lane >> 4;
  int srow = wave*32 + (lane >> 2);
  int sko  = ((lane & 3) ^ ((lane >> 3) & 3)) * 8;
  const unsigned short* gah = Ah + (size_t)(m0 + srow)*Kp + sko;
  const unsigned short* gal = Al + (size_t)(m0 + srow)*Kp + sko;
  int seg2 = 16*Kp;
  int lws = wave*1024;
  const unsigned short* pbh = Bh + (size_t)(n0 + wn + l15)*Kp + quad*8;
  const unsigned short* pbl = Bl + (size_t)(n0 + wn + l15)*Kp + quad*8;
  GLDS(gah, &sAh[0][lws]);  GLDS(gah + seg2, &sAh[0][lws + 512]);
  GLDS(gal, &sAl[0][lws]);  GLDS(gal + seg2, &sAl[0][lws + 512]);
  f32x4 acc[4][4] = {};
  int nk = Kp >> 5;
  int kq = (quad ^ ((l15 >> 1) & 3)) * 8;
  for (int tt = 0; tt < nk; ++tt) {
    int k0 = tt << 5;
    int cur = tt & 1;
    __syncthreads();
    bf16x8 fbh[4], fbl[4];
    #pragma unroll
    for (int j = 0; j < 4; ++j) {
      size_t off = (size_t)(j*16)*Kp + k0;
      fbh[j] = *(const bf16x8*)(pbh + off);
      fbl[j] = *(const bf16x8*)(pbl + off);
    }
    if (tt + 1 < nk) {
      int nxt = cur ^ 1;
      GLDS(gah + k0+32, &sAh[nxt][lws]);  GLDS(gah + k0+32 + seg2, &sAh[nxt][lws + 512]);
      GLDS(gal + k0+32, &sAl[nxt][lws]);  GLDS(gal + k0+32 + seg2, &sAl[nxt][lws + 512]);
    }
    bf16x8 fah[4], fal[4];
    #pragma unroll
    for (int i = 0; i < 4; ++i) {
      int ra = (wm + i*16 + l15)*32 + kq;
      fah[i] = *(const bf16x8*)&sAh[cur][ra];
      fal[i] = *(const bf16x8*)&sAl[cur][ra];
    }
    #pragma unroll
    for (int i = 0; i < 4; ++i)
      #pragma unroll
      for (int j = 0; j < 4; ++j) {
        acc[i][j] = __builtin_amdgcn_mfma_f32_16x16x32_bf16(fah[i], fbl[j], acc[i][j], 0, 0, 0);
        acc[i][j] = __builtin_amdgcn_mfma_f32_16x16x32_bf16(fal[i], fbh[j], acc[i][j], 0, 0, 0);
        acc[i][j] = __builtin_amdgcn_mfma_f32_16x16x32_bf16(fah[i], fbh[j], acc[i][j], 0, 0, 0);
      }
  }
  #pragma unroll
  for (int i = 0; i < 4; ++i) {
    #pragma unroll
    for (int j = 0; j < 4; ++j) {
      int col = n0 + wn + j*16 + l15;
      if (col >= N) continue;
      float bv = bias[col];
      #pragma unroll
      for (int r = 0; r < 4; ++r) {
        int row = m0 + wm + i*16 + quad*4 + r;
        C[(size_t)row*N + col] = acc[i][j][r] + bv;
      }
    }
  }
}

// ---------- 3. per-row L2 normalize -> 3 bf16 planes, PADDED [.][KP2] ----------
__global__ __launch_bounds__(256) void rownorm_k(const float* __restrict__ xp,
                          unsigned short* __restrict__ y0, unsigned short* __restrict__ y1,
                          unsigned short* __restrict__ y2) {
  int lane = threadIdx.x & 63;
  int n = blockIdx.x*4 + (threadIdx.x >> 6);
  const float* r = xp + (size_t)n*EC;
  float ss = 0.f;
  for (int e = lane; e < EC; e += 64) { float v = r[e]; ss += v*v; }
  #pragma unroll
  for (int off = 32; off > 0; off >>= 1) ss += __shfl_down(ss, off);
  float nrm = sqrtf(__shfl(ss, 0));
  float s = 1.f / fmaxf(nrm, 1e-12f);
  for (int e = lane; e < KP2; e += 64) {
    unsigned short a = 0, b = 0, c = 0;
    if (e < EC) { float v = r[e]*s; split3_(v, a, b, c); }
    y0[(size_t)n*KP2 + e] = a;
    y1[(size_t)n*KP2 + e] = b;
    y2[(size_t)n*KP2 + e] = c;
  }
}

// ---------- 5. per-token head attention (kh=1 => argmax gather) ----------
__global__ __launch_bounds__(64) void attn_k(const float* __restrict__ qkv, float* __restrict__ outS,
                      float* __restrict__ imp) {
  __shared__ float row[E3];
  __shared__ float sc[36];
  __shared__ int sel[6];
  int t = threadIdx.x;
  int n = blockIdx.x;
  const float4* src = (const float4*)(qkv + (size_t)n * E3);
  for (int i = t; i < 252; i += 64) ((float4*)row)[i] = src[i];
  __syncthreads();
  if (t < 36) {
    int h = t / 6, g = t % 6;
    const float* q = row + h*HDC;
    const float* kk = row + EC + g*HDC;
    float s = 0.f;
    #pragma unroll
    for (int d = 0; d < HDC; ++d) s += q[d]*kk[d];
    sc[t] = s;
  }
  __syncthreads();
  if (t < 6) {
    float best = sc[t*6]; int bi = 0;
    #pragma unroll
    for (int g = 1; g < 6; ++g) { float vv = sc[t*6+g]; if (vv > best) { best = vv; bi = g; } }
    sel[t] = bi;
  }
  __syncthreads();
  float ss = 0.f;
  for (int e = t; e < EC; e += 64) {
    int d = e / 6, h = e - d*6;       // channel c = d*HEADS + h
    float vv = row[2*EC + sel[h]*HDC + d];
    outS[(size_t)n*EC + e] = vv;
    ss += vv*vv;
  }
  #pragma unroll
  for (int off = 32; off > 0; off >>= 1) ss += __shfl_down(ss, off);
  if (t == 0) imp[n] = sqrtf(ss);
}

// ---------- 6. top-819 of 4096 per batch: exact radix-select + 1024-bitonic ----------
__global__ __launch_bounds__(1024) void topk_k(const float* __restrict__ imp, int* __restrict__ idxb,
                       int* __restrict__ map) {
  __shared__ unsigned hist[257];
  __shared__ unsigned selNeed, selPrefix, cnt;
  __shared__ unsigned cv[1024];
  __shared__ int ci[1024];
  int b = blockIdx.x, t = threadIdx.x;
  unsigned key[4];
  #pragma unroll
  for (int j = 0; j < 4; ++j) key[j] = __float_as_uint(imp[b*4096 + j*1024 + t]);
  #pragma unroll
  for (int j = 0; j < 4; ++j) map[b*4096 + j*1024 + t] = -1;   // init; re-written below for selected
  if (t == 0) { selNeed = KC; selPrefix = 0u; cnt = 0u; }
  __syncthreads();
  // 4 MSB-first passes; invariant: current class (prefix) holds >= selNeed keys
  for (int pass = 0; pass < 4; ++pass) {
    int sh = 24 - pass*8;
    if (t < 257) hist[t] = 0u;
    __syncthreads();
    unsigned pfx = selPrefix;
    #pragma unroll
    for (int j = 0; j < 4; ++j) {
      unsigned k = key[j];
      bool in = (pass == 0) || ((k >> (sh + 8)) == pfx);
      if (in) atomicAdd(&hist[(k >> sh) & 0xFFu], 1u);
    }
    __syncthreads();
    // parallel suffix sum: hist[i] := count(digit >= i)
    for (int off = 1; off < 256; off <<= 1) {
      unsigned v2 = 0u;
      if (t < 256 && t + off < 256) v2 = hist[t + off];
      __syncthreads();
      if (t < 256) hist[t] += v2;
      __syncthreads();
    }
    unsigned need = selNeed;
    __syncthreads();
    if (t < 256) {
      unsigned c0 = hist[t];
      unsigned c1 = (t < 255) ? hist[t+1] : 0u;
      if (c0 >= need && c1 < need) {       // unique crossing bin
        selNeed = need - c1;
        selPrefix = (pfx << 8) | (unsigned)t;
      }
    }
    __syncthreads();
  }
  unsigned K819 = selPrefix;               // exact KC-th largest key
  // gather all keys >= K819 (~KC of them; ties resolved by the sort below)
  #pragma unroll
  for (int j = 0; j < 4; ++j) {
    if (key[j] >= K819) {
      unsigned pos = atomicAdd(&cnt, 1u);
      if (pos < 1024u) { cv[pos] = key[j]; ci[pos] = j*1024 + t; }
    }
  }
  __syncthreads();
  unsigned total = cnt < 1024u ? cnt : 1024u;
  if ((unsigned)t >= total) { cv[t] = 0u; ci[t] = 0x7FFFFFFF; }
  __syncthreads();
  // bitonic sort 1024 by (value desc, index asc)
  for (int k = 2; k <= 1024; k <<= 1) {
    for (int j = k >> 1; j > 0; j >>= 1) {
      int p = t ^ j;
      if (p > t) {
        unsigned va = cv[t], vb = cv[p];
        int ia = ci[t], ib = ci[p];
        bool aFirst = (va > vb) || (va == vb && ia < ib);
        bool up = ((t & k) == 0);
        if (up ? !aFirst : aFirst) { cv[t] = vb; cv[p] = va; ci[t] = ib; ci[p] = ia; }
      }
      __syncthreads();
    }
  }
  if (t < KC) {
    int l = ci[t];
    idxb[b*KC + t] = l;
    map[b*4096 + l] = t;
  }
}

// ---------- 7a+7b fused: per-channel composed kernel K2[e][0..TRUNC) ----------
__global__ __launch_bounds__(256) void ssmk_k(const float* __restrict__ A, const float* __restrict__ Bp,
                      const float* __restrict__ Cp, const float* __restrict__ convw,
                      float* __restrict__ K2) {
  __shared__ float Ab[256], Pb[256], Tb[256];
  __shared__ float V[TRUNC][16];
  __shared__ float K1[TRUNC];
  int e = blockIdx.x, t = threadIdx.x;
  int r = t >> 4, c = t & 15;
  Ab[t] = A[t];
  __syncthreads();
  float x;
  x = 0.f;
  #pragma unroll
  for (int k = 0; k < 16; ++k) x += Ab[r*16+k]*Ab[k*16+c];
  Pb[t] = x; __syncthreads();                 // A^2
  x = 0.f;
  #pragma unroll
  for (int k = 0; k < 16; ++k) x += Pb[r*16+k]*Pb[k*16+c];
  Tb[t] = x; __syncthreads();                 // A^4
  x = 0.f;
  #pragma unroll
  for (int k = 0; k < 16; ++k) x += Tb[r*16+k]*Tb[k*16+c];
  Pb[t] = x; __syncthreads();                 // A^8
  x = 0.f;
  #pragma unroll
  for (int k = 0; k < 16; ++k) x += Pb[r*16+k]*Pb[k*16+c];
  Tb[t] = x; __syncthreads();                 // A^16
  if (t < 16) V[0][t] = sigmoidf_(Bp[t]);
  __syncthreads();
  for (int j = 1; j < 16; ++j) {
    if (t < 16) {
      float s = 0.f;
      #pragma unroll
      for (int k = 0; k < 16; ++k) s += Ab[t*16+k]*V[j-1][k];
      V[j][t] = s;
    }
    __syncthreads();
  }
  for (int sg = 1; sg < TRUNC/16; ++sg) {     // V[16sg+g] = A^16 V[16(sg-1)+g]
    int g = t >> 4, rr = t & 15;
    float s = 0.f;
    #pragma unroll
    for (int k = 0; k < 16; ++k) s += Tb[rr*16+k]*V[16*(sg-1)+g][k];
    V[16*sg+g][rr] = s;
    __syncthreads();
  }
  float sC[16];
  #pragma unroll
  for (int s = 0; s < 16; ++s) sC[s] = sigmoidf_(Cp[e*16+s]);
  for (int i = t; i < TRUNC; i += 256) {
    float s = 0.f;
    #pragma unroll
    for (int k = 0; k < 16; ++k) s += sC[k]*V[i][k];
    K1[i] = s;
  }
  __syncthreads();
  float w0 = convw[e*4+0], w1 = convw[e*4+1], w2 = convw[e*4+2], w3 = convw[e*4+3];
  for (int m = t; m < TRUNC; m += 256) {
    float acc = w3*K1[m];
    if (m >= 1) acc += w2*K1[m-1];
    if (m >= 2) acc += w1*K1[m-2];
    if (m >= 3) acc += w0*K1[m-3];
    K2[(size_t)e*TRUNC + m] = acc;
  }
}

// ---------- 7c. fused gather+conv+scan (TRUNC taps) -> Yt fp32 [e][b*KCP+tt] ----------
#define XSZ (TRUNC + KC + 8)
#define XSWZ (XSZ + XSZ/32 + 2)
__device__ __forceinline__ int swz_(int i){ return i + (i>>5); }
__global__ __launch_bounds__(128) void ssmconv_k(const float* __restrict__ outS, const int* __restrict__ idxb,
                         const float* __restrict__ K2, float* __restrict__ Yt) {
  __shared__ float X[XSWZ];
  __shared__ float Ks[TRUNC];
  int bid = blockIdx.x;
  int b = bid & 7, e = bid >> 3, t = threadIdx.x;
  for (int i = t; i < XSWZ; i += 128) X[i] = 0.f;
  __syncthreads();
  for (int i = t; i < KC; i += 128) {
    int l = idxb[b*KC + i];
    X[swz_(TRUNC + i)] = outS[((size_t)(b*LL + l))*EC + e];
  }
  for (int i = t; i < TRUNC; i += 128) Ks[i] = K2[(size_t)e*TRUNC + i];
  __syncthreads();
  int t0 = t*8;
  if (t0 < KC) {
    int base = TRUNC + t0;
    float a0=0,a1=0,a2=0,a3=0,a4=0,a5=0,a6=0,a7=0;
    float r0=X[swz_(base+0)], r1=X[swz_(base+1)], r2=X[swz_(base+2)], r3=X[swz_(base+3)];
    float r4=X[swz_(base+4)], r5=X[swz_(base+5)], r6=X[swz_(base+6)], r7=X[swz_(base+7)];
    #pragma unroll 4
    for (int m = 0; m < TRUNC; m += 8) {
      float4 k0 = *(const float4*)&Ks[m];
      float4 k1 = *(const float4*)&Ks[m+4];
      float kv;
      kv = k0.x;
      a0+=kv*r0; a1+=kv*r1; a2+=kv*r2; a3+=kv*r3; a4+=kv*r4; a5+=kv*r5; a6+=kv*r6; a7+=kv*r7;
      r7=r6; r6=r5; r5=r4; r4=r3; r3=r2; r2=r1; r1=r0; r0=X[swz_(base-m-1)];
      kv = k0.y;
      a0+=kv*r0; a1+=kv*r1; a2+=kv*r2; a3+=kv*r3; a4+=kv*r4; a5+=kv*r5; a6+=kv*r6; a7+=kv*r7;
      r7=r6; r6=r5; r5=r4; r4=r3; r3=r2; r2=r1; r1=r0; r0=X[swz_(base-m-2)];
      kv = k0.z;
      a0+=kv*r0; a1+=kv*r1; a2+=kv*r2; a3+=kv*r3; a4+=kv*r4; a5+=kv*r5; a6+=kv*r6; a7+=kv*r7;
      r7=r6; r6=r5; r5=r4; r4=r3; r3=r2; r2=r1; r1=r0; r0=X[swz_(base-m-3)];
      kv = k0.w;
      a0+=kv*r0; a1+=kv*r1; a2+=kv*r2; a3+=kv*r3; a4+=kv*r4; a5+=kv*r5; a6+=kv*r6; a7+=kv*r7;
      r7=r6; r6=r5; r5=r4; r4=r3; r3=r2; r2=r1; r1=r0; r0=X[swz_(base-m-4)];
      kv = k1.x;
      a0+=kv*r0; a1+=kv*r1; a2+=kv*r2; a3+=kv*r3; a4+=kv*r4; a5+=kv*r5; a6+=kv*r6; a7+=kv*r7;
      r7=r6; r6=r5; r5=r4; r4=r3; r3=r2; r2=r1; r1=r0; r0=X[swz_(base-m-5)];
      kv = k1.y;
      a0+=kv*r0; a1+=kv*r1; a2+=kv*r2; a3+=kv*r3; a4+=kv*r4; a5+=kv*r5; a6+=kv*r6; a7+=kv*r7;
      r7=r6; r6=r5; r5=r4; r4=r3; r3=r2; r2=r1; r1=r0; r0=X[swz_(base-m-6)];
      kv = k1.z;
      a0+=kv*r0; a1+=kv*r1; a2+=kv*r2; a3+=kv*r3; a4+=kv*r4; a5+=kv*r5; a6+=kv*r6; a7+=kv*r7;
      r7=r6; r6=r5; r5=r4; r4=r3; r3=r2; r2=r1; r1=r0; r0=X[swz_(base-m-7)];
      kv = k1.w;
      a0+=kv*r0; a1+=kv*r1; a2+=kv*r2; a3+=kv*r3; a4+=kv*r4; a5+=kv*r5; a6+=kv*r6; a7+=kv*r7;
      r7=r6; r6=r5; r5=r4; r4=r3; r3=r2; r2=r1; r1=r0; r0=X[swz_(base-m-8)];
    }
    float acc[8] = {a0,a1,a2,a3,a4,a5,a6,a7};
    float* dst = Yt + (size_t)e*YTS + b*KCP + t0;
    #pragma unroll
    for (int i = 0; i < 8; ++i) {
      if (t0 + i < KC) dst[i] = acc[i];     // contiguous per-thread run: coalesced
    }
  }
}

// ---------- 7d. transpose + split: Yt [336][YTS] fp32 -> ysh/ysl PADDED [YTS][KP2] bf16 ----------
__global__ __launch_bounds__(256) void tsplit_k(const float* __restrict__ Yt,
                         unsigned short* __restrict__ ysh, unsigned short* __restrict__ ysl) {
  __shared__ float T[32][33];
  int tb = blockIdx.x;          // token tile: 0..25 (26*32 = 832 = KCP)
  int eb = blockIdx.y;          // channel tile: 0..10 (11*32 = 352 = KP2)
  int b  = blockIdx.z;
  int tx = threadIdx.x & 31, ty = threadIdx.x >> 5;   // 32 x 8
  int t0 = tb*32, e0 = eb*32;
  #pragma unroll
  for (int j = 0; j < 4; ++j) {
    int e = e0 + ty + j*8;
    T[ty + j*8][tx] = (e < EC) ? Yt[(size_t)e*YTS + b*KCP + t0 + tx] : 0.f;
  }
  __syncthreads();
  #pragma unroll
  for (int j = 0; j < 4; ++j) {
    int tt = t0 + ty + j*8;
    int e  = e0 + tx;
    float v = (tt < KC && e < EC) ? T[tx][ty + j*8] : 0.f;
    unsigned short h = bf16rn_(v);
    size_t off = ((size_t)(b*KCP + tt))*KP2 + e;
    ysh[off] = h;
    ysl[off] = bf16rn_(v - bf2f_(h));
  }
}

// ---------- 9. epilogue: out = x + scatter(xproc by map) ----------
__global__ __launch_bounds__(256) void epi_k(const float* __restrict__ x, const float* __restrict__ xproc,
                      const int* __restrict__ map, float* __restrict__ out) {
  size_t i = (size_t)blockIdx.x*256 + threadIdx.x;  // float4 index over 4194304
  int row = (int)(i >> 7);
  int c = ((int)i & 127) << 2;
  int b = row >> 12;
  float4 v = ((const float4*)x)[i];
  int m = map[row];
  if (m >= 0) {
    const float4 pv = *(const float4*)(xproc + ((size_t)(b*KCP + m))*DIMC + c);
    v.x += pv.x; v.y += pv.y; v.z += pv.z; v.w += pv.w;
  }
  ((float4*)out)[i] = v;
}

extern "C" void kernel_launch(void* const* d_in, const int* in_sizes, int n_in,
                              void* d_out, int out_size, void* d_ws, size_t ws_size,
                              hipStream_t stream) {
  const float* x     = (const float*)d_in[0];
  const float* alpha = (const float*)d_in[1];
  const float* dyt_w = (const float*)d_in[2];
  const float* dyt_b = (const float*)d_in[3];
  const float* W_in  = (const float*)d_in[4];
  const float* b_in  = (const float*)d_in[5];
  const float* W_qkv = (const float*)d_in[6];
  const float* b_qkv = (const float*)d_in[7];
  const float* convw = (const float*)d_in[8];
  const float* A     = (const float*)d_in[9];
  const float* Bp    = (const float*)d_in[10];
  const float* Cp    = (const float*)d_in[11];
  const float* W_out = (const float*)d_in[12];
  const float* b_out = (const float*)d_in[13];

  float* outF = (float*)d_out;          // scratch: attn-out (32768x336), then final output

  float* ws = (float*)d_ws;
  // ---- full-batch layout (~218 MB) ----
  unsigned short* xn0  = (unsigned short*)(ws + 0);          // NN*512 bf16 = 8,388,608 f
  unsigned short* xn1  = (unsigned short*)(ws + 8388608);
  unsigned short* xn2  = (unsigned short*)(ws + 16777216);
  float*          xp   = ws + 25165824;                      // NN*336 = 11,010,048 f
  float*          qkv  = ws + 0;                             // NN*1008 = 33,030,144 f (overlays xn+xp)
  // persistent (padded planes):
  unsigned short* xpn0 = (unsigned short*)(ws + 36175872);   // NN*KP2 bf16 = 5,767,168 f each
  unsigned short* xpn1 = (unsigned short*)(ws + 41943040);
  unsigned short* xpn2 = (unsigned short*)(ws + 47710208);
  float*          imp  = ws + 53477376;                      // 32768 f
  int*            idxb = (int*)(ws + 53510144);              // 8192 slots
  int*            mapb = (int*)(ws + 53518336);              // 32768
  unsigned short* wi0  = (unsigned short*)(ws + 53551104);   // NP1*512 bf16 = 98,304 f each
  unsigned short* wi1  = (unsigned short*)(ws + 53649408);
  unsigned short* wi2  = (unsigned short*)(ws + 53747712);
  unsigned short* wq0  = (unsigned short*)(ws + 53846016);   // NP2*KP2 bf16 = 180,224 f each
  unsigned short* wq1  = (unsigned short*)(ws + 54026240);
  unsigned short* wq2  = (unsigned short*)(ws + 54206464);
  unsigned short* woh  = (unsigned short*)(ws + 54386688);   // 512*KP2 bf16 = 90,112 f each
  unsigned short* wol  = (unsigned short*)(ws + 54476800);   // end 54,566,912 f = 218.3 MB
  // overlays on R0 after attn_k (qkv dead):
  float*          K2    = ws + 0;                            // 336*160 = 53,760 f
  unsigned short* ysh   = (unsigned short*)(ws + 53760);     // YTS*KP2 bf16 = 1,171,456 f each
  unsigned short* ysl   = (unsigned short*)(ws + 1225216);
  float*          Yt    = ws + 2396672;                      // 336*YTS = 2,236,416 f
  float*          xproc = ws + 4633088;                      // YTS*512 = 3,407,872 f (end 8,040,960)

  // 0. transpose+split weights (padded planes)
  prepw3x2_k<<<(NP1*DIMC + NP2*KP2 + 255)/256, 256, 0, stream>>>(W_in, wi0, wi1, wi2,
                                                                 W_qkv, wq0, wq1, wq2);
  prepwo_k<<<(DIMC*KP2 + 255)/256, 256, 0, stream>>>(W_out, woh, wol);

  // 1-5 full batch, single dispatches
  dyt_k<<<NN*DIMC/1024, 256, 0, stream>>>(x, xn0, xn1, xn2, alpha, dyt_w, dyt_b);
  mgemm6_k<<<dim3(NP1/128, NN/128), 256, 0, stream>>>(xn0, xn1, xn2, wi0, wi1, wi2, b_in, xp, EC, DIMC);
  rownorm_k<<<NN/4, 256, 0, stream>>>(xp, xpn0, xpn1, xpn2);
  mgemm6_k<<<dim3(NP2/128, NN/128), 256, 0, stream>>>(xpn0, xpn1, xpn2, wq0, wq1, wq2, b_qkv, qkv, E3, KP2);
  attn_k<<<NN, 64, 0, stream>>>(qkv, outF, imp);

  // 6. top-k per batch (radix select + small sort)
  topk_k<<<BB, 1024, 0, stream>>>(imp, idxb, mapb);
  // 7. composed SSM kernel + fused conv
  ssmk_k<<<EC, 256, 0, stream>>>(A, Bp, Cp, convw, K2);
  ssmconv_k<<<EC*BB, 128, 0, stream>>>(outF, idxb, K2, Yt);
  // 7d. transpose+split Yt -> padded ysh/ysl [token][channel]
  tsplit_k<<<dim3(KCP/32, KP2/32, BB), 256, 0, stream>>>(Yt, ysh, ysl);
  // 9. xproc = ys @ W_out + b_out (dbuf gload_lds A + direct-B, padded M=6656/K=352)
  mgemm3_k<<<dim3(4, YTS/128), 256, 0, stream>>>(ysh, ysl, woh, wol, b_out, xproc, DIMC, KP2);
  // 10. output = x + scatter(xproc)
  epi_k<<<16384, 256, 0, stream>>>(x, xproc, mapb, outF);
}

// Round 7
// 506.115 us; speedup vs baseline: 1.0749x; 1.0749x over previous
//
#include <hip/hip_runtime.h>
#include <math.h>

#define DIMC 512
#define EC   336
#define E3   1008
#define HDC  56
#define BB   8
#define LL   4096
#define NN   32768
#define KC   819
#define KCP  832        // padded per-batch token stride (multiple of 32)
#define YTS  (BB*KCP)   // 6656: Yt row stride (per channel); also padded G3 M
#define TRUNC 160   // effective taps: |K2[m]| ~ rho^m, rho<~0.5 => tail < 1e-40 at 160

// padded dims for the MFMA GEMMs (zero-padded => bit-identical results)
#define KP2  352    // K: 336 -> 352 (multiple of 32) for GEMM2/GEMM3
#define NP1  384    // B-rows for GEMM1: 336 -> 384 (multiple of 128)
#define NP2  1024   // B-rows for GEMM2: 1008 -> 1024 (multiple of 128)

typedef short bf16x8 __attribute__((ext_vector_type(8)));
typedef float f32x4 __attribute__((ext_vector_type(4)));

__device__ __forceinline__ float sigmoidf_(float x){ return 1.f/(1.f+expf(-x)); }
__device__ __forceinline__ unsigned short bf16rn_(float x){
  unsigned u = __float_as_uint(x);
  unsigned r = (u + 0x7FFFu + ((u>>16)&1u)) >> 16;
  return (unsigned short)r;
}
__device__ __forceinline__ float bf2f_(unsigned short h){ return __uint_as_float(((unsigned)h)<<16); }

// 3-way split: x ~= p0 + p1 + p2, residual ~2^-27 relative
__device__ __forceinline__ void split3_(float v, unsigned short& p0, unsigned short& p1, unsigned short& p2){
  p0 = bf16rn_(v);           float r1 = v - bf2f_(p0);
  p1 = bf16rn_(r1);          float r2 = r1 - bf2f_(p1);
  p2 = bf16rn_(r2);
}

#define GLDS(g, l) __builtin_amdgcn_global_load_lds( \
    (const __attribute__((address_space(1))) unsigned int*)(g), \
    (__attribute__((address_space(3))) unsigned int*)(l), 16, 0, 0)

// ---------- weight prep: W_in and W_qkv -> 3 bf16 planes, PADDED [Np][Kp] ----------
__global__ __launch_bounds__(256) void prepw3x2_k(const float* __restrict__ Wa,
    unsigned short* __restrict__ A0, unsigned short* __restrict__ A1, unsigned short* __restrict__ A2,
    const float* __restrict__ Wb,
    unsigned short* __restrict__ B0, unsigned short* __restrict__ B1, unsigned short* __restrict__ B2) {
  int i = blockIdx.x*256 + threadIdx.x;
  const int na = NP1*DIMC;     // W_in^T padded: [384][512]
  const int nb = NP2*KP2;      // W_qkv^T padded: [1024][352]
  if (i < na) {
    int n = i >> 9, k = i & 511;
    float w = (n < EC) ? Wa[(size_t)k*EC + n] : 0.f;
    unsigned short a,b,c; split3_(w, a, b, c);
    A0[i] = a; A1[i] = b; A2[i] = c;
  } else {
    int i2 = i - na;
    if (i2 < nb) {
      int n = i2 / KP2, k = i2 - n*KP2;
      float w = (n < E3 && k < EC) ? Wb[(size_t)k*E3 + n] : 0.f;
      unsigned short a,b,c; split3_(w, a, b, c);
      B0[i2] = a; B1[i2] = b; B2[i2] = c;
    }
  }
}
// 2-plane variant for W_out, PADDED [512][352]
__global__ __launch_bounds__(256) void prepwo_k(const float* __restrict__ W,
                        unsigned short* __restrict__ Th, unsigned short* __restrict__ Tl) {
  int i = blockIdx.x*256 + threadIdx.x;
  if (i >= DIMC*KP2) return;
  int n = i / KP2, k = i - n*KP2;
  float w = (k < EC) ? W[(size_t)k*DIMC + n] : 0.f;
  unsigned short h = bf16rn_(w);
  Th[i] = h;
  Tl[i] = bf16rn_(w - bf2f_(h));
}

// ---------- 1. DyT (full batch): xn = tanh(alpha*x)*w + b -> 3 bf16 planes ----------
__global__ __launch_bounds__(256) void dyt_k(const float* __restrict__ x, unsigned short* __restrict__ x0,
                      unsigned short* __restrict__ x1, unsigned short* __restrict__ x2,
                      const float* __restrict__ alpha, const float* __restrict__ dw,
                      const float* __restrict__ db) {
  size_t i = (size_t)blockIdx.x*256 + threadIdx.x;   // float4 index over NN*512/4
  int c = ((int)(i & 127)) << 2;
  float a = alpha[0];
  float4 v = ((const float4*)x)[i];
  float o[4];
  o[0] = tanhf(a*v.x)*dw[c+0]+db[c+0];
  o[1] = tanhf(a*v.y)*dw[c+1]+db[c+1];
  o[2] = tanhf(a*v.z)*dw[c+2]+db[c+2];
  o[3] = tanhf(a*v.w)*dw[c+3]+db[c+3];
  ushort4 a0, a1, a2;
  split3_(o[0], a0.x, a1.x, a2.x);
  split3_(o[1], a0.y, a1.y, a2.y);
  split3_(o[2], a0.z, a1.z, a2.z);
  split3_(o[3], a0.w, a1.w, a2.w);
  ((ushort4*)x0)[i] = a0;
  ((ushort4*)x1)[i] = a1;
  ((ushort4*)x2)[i] = a2;
}

// ---------- MFMA fp32-emulated GEMM: 3 bf16 planes each side, 6 terms ----------
// global_load_lds staging (width 16), linear [128][32] LDS with chunk-XOR swizzle:
// LDS slot (row, c) holds global k-chunk c ^ ((row>>1)&3)  [rule #21: pre-swizzled
// global source + swizzled read addr; LDS dest stays linear]. Read bank pattern per
// 16-lane quad: 8 four-bank groups x 2 lanes = 2-way (free, m136).
__global__ __launch_bounds__(256,3) void mgemm6_k(const unsigned short* __restrict__ A0,
    const unsigned short* __restrict__ A1, const unsigned short* __restrict__ A2,
    const unsigned short* __restrict__ B0, const unsigned short* __restrict__ B1,
    const unsigned short* __restrict__ B2, const float* __restrict__ bias,
    float* __restrict__ C, int N, int Kp) {
  __shared__ unsigned short sA0[128*32], sA1[128*32], sA2[128*32];
  __shared__ unsigned short sB0[128*32], sB1[128*32], sB2[128*32];
  int t = threadIdx.x;
  int nwg = gridDim.x*gridDim.y;          // 768 (G1) / 2048 (G2): % 8 == 0
  int bid = blockIdx.y*gridDim.x + blockIdx.x;
  int cpx = nwg >> 3;
  int swz = (bid & 7)*cpx + (bid >> 3);
  int by = swz / gridDim.x;
  int bx = swz - by*gridDim.x;
  int m0 = by*128, n0 = bx*128;
  int wave = t >> 6, lane = t & 63;
  int wm = (wave & 1)*64, wn = (wave >> 1)*64;
  int l15 = lane & 15, quad = lane >> 4;
  int srow = wave*32 + (lane >> 2);
  int sko  = ((lane & 3) ^ ((lane >> 3) & 3)) * 8;   // chunk-XOR pre-swizzled source
  const unsigned short* ga0 = A0 + (size_t)(m0 + srow)*Kp + sko;
  const unsigned short* ga1 = A1 + (size_t)(m0 + srow)*Kp + sko;
  const unsigned short* ga2 = A2 + (size_t)(m0 + srow)*Kp + sko;
  const unsigned short* gb0 = B0 + (size_t)(n0 + srow)*Kp + sko;
  const unsigned short* gb1 = B1 + (size_t)(n0 + srow)*Kp + sko;
  const unsigned short* gb2 = B2 + (size_t)(n0 + srow)*Kp + sko;
  int seg2 = 16*Kp;
  unsigned short* la0 = &sA0[wave*1024];
  unsigned short* la1 = &sA1[wave*1024];
  unsigned short* la2 = &sA2[wave*1024];
  unsigned short* lb0 = &sB0[wave*1024];
  unsigned short* lb1 = &sB1[wave*1024];
  unsigned short* lb2 = &sB2[wave*1024];
  f32x4 acc[4][4] = {};
  for (int k0 = 0; k0 < Kp; k0 += 32) {
    __syncthreads();
    GLDS(ga0 + k0, la0);  GLDS(ga0 + k0 + seg2, la0 + 512);
    GLDS(ga1 + k0, la1);  GLDS(ga1 + k0 + seg2, la1 + 512);
    GLDS(ga2 + k0, la2);  GLDS(ga2 + k0 + seg2, la2 + 512);
    GLDS(gb0 + k0, lb0);  GLDS(gb0 + k0 + seg2, lb0 + 512);
    GLDS(gb1 + k0, lb1);  GLDS(gb1 + k0 + seg2, lb1 + 512);
    GLDS(gb2 + k0, lb2);  GLDS(gb2 + k0 + seg2, lb2 + 512);
    __syncthreads();
    bf16x8 fa0[4], fa1[4], fa2[4], fb0[4], fb1[4], fb2[4];
    int kq = (quad ^ ((l15 >> 1) & 3)) * 8;           // swizzled read chunk
    #pragma unroll
    for (int i = 0; i < 4; ++i) {
      int ra = (wm + i*16 + l15)*32 + kq;
      fa0[i] = *(const bf16x8*)&sA0[ra];
      fa1[i] = *(const bf16x8*)&sA1[ra];
      fa2[i] = *(const bf16x8*)&sA2[ra];
      int rb = (wn + i*16 + l15)*32 + kq;
      fb0[i] = *(const bf16x8*)&sB0[rb];
      fb1[i] = *(const bf16x8*)&sB1[rb];
      fb2[i] = *(const bf16x8*)&sB2[rb];
    }
    #pragma unroll
    for (int i = 0; i < 4; ++i)
      #pragma unroll
      for (int j = 0; j < 4; ++j) {
        acc[i][j] = __builtin_amdgcn_mfma_f32_16x16x32_bf16(fa1[i], fb1[j], acc[i][j], 0, 0, 0);
        acc[i][j] = __builtin_amdgcn_mfma_f32_16x16x32_bf16(fa0[i], fb2[j], acc[i][j], 0, 0, 0);
        acc[i][j] = __builtin_amdgcn_mfma_f32_16x16x32_bf16(fa2[i], fb0[j], acc[i][j], 0, 0, 0);
        acc[i][j] = __builtin_amdgcn_mfma_f32_16x16x32_bf16(fa0[i], fb1[j], acc[i][j], 0, 0, 0);
        acc[i][j] = __builtin_amdgcn_mfma_f32_16x16x32_bf16(fa1[i], fb0[j], acc[i][j], 0, 0, 0);
        acc[i][j] = __builtin_amdgcn_mfma_f32_16x16x32_bf16(fa0[i], fb0[j], acc[i][j], 0, 0, 0);
      }
  }
  #pragma unroll
  for (int i = 0; i < 4; ++i) {
    #pragma unroll
    for (int j = 0; j < 4; ++j) {
      int col = n0 + wn + j*16 + l15;
      if (col >= N) continue;
      float bv = bias[col];
      #pragma unroll
      for (int r = 0; r < 4; ++r) {
        int row = m0 + wm + i*16 + quad*4 + r;
        C[(size_t)row*N + col] = acc[i][j][r] + bv;
      }
    }
  }
}

// ---------- MFMA bf16x3 GEMM (2 planes, 3 terms), gload_lds + swizzle — GEMM3 ----------
__global__ __launch_bounds__(256,2) void mgemm3_k(const unsigned short* __restrict__ Ah,
    const unsigned short* __restrict__ Al, const unsigned short* __restrict__ Bh,
    const unsigned short* __restrict__ Bl, const float* __restrict__ bias,
    float* __restrict__ C, int N, int Kp) {
  __shared__ unsigned short sAh[128*32], sAl[128*32], sBh[128*32], sBl[128*32];
  int t = threadIdx.x;
  int nwg = gridDim.x*gridDim.y;          // 208: % 8 == 0
  int bid = blockIdx.y*gridDim.x + blockIdx.x;
  int cpx = nwg >> 3;
  int swz = (bid & 7)*cpx + (bid >> 3);
  int by = swz / gridDim.x;
  int bx = swz - by*gridDim.x;
  int m0 = by*128, n0 = bx*128;
  int wave = t >> 6, lane = t & 63;
  int wm = (wave & 1)*64, wn = (wave >> 1)*64;
  int l15 = lane & 15, quad = lane >> 4;
  int srow = wave*32 + (lane >> 2);
  int sko  = ((lane & 3) ^ ((lane >> 3) & 3)) * 8;
  const unsigned short* gah = Ah + (size_t)(m0 + srow)*Kp + sko;
  const unsigned short* gal = Al + (size_t)(m0 + srow)*Kp + sko;
  const unsigned short* gbh = Bh + (size_t)(n0 + srow)*Kp + sko;
  const unsigned short* gbl = Bl + (size_t)(n0 + srow)*Kp + sko;
  int seg2 = 16*Kp;
  unsigned short* lah = &sAh[wave*1024];
  unsigned short* lal = &sAl[wave*1024];
  unsigned short* lbh = &sBh[wave*1024];
  unsigned short* lbl = &sBl[wave*1024];
  f32x4 acc[4][4] = {};
  for (int k0 = 0; k0 < Kp; k0 += 32) {
    __syncthreads();
    GLDS(gah + k0, lah);  GLDS(gah + k0 + seg2, lah + 512);
    GLDS(gal + k0, lal);  GLDS(gal + k0 + seg2, lal + 512);
    GLDS(gbh + k0, lbh);  GLDS(gbh + k0 + seg2, lbh + 512);
    GLDS(gbl + k0, lbl);  GLDS(gbl + k0 + seg2, lbl + 512);
    __syncthreads();
    bf16x8 fah[4], fal[4], fbh[4], fbl[4];
    int kq = (quad ^ ((l15 >> 1) & 3)) * 8;
    #pragma unroll
    for (int i = 0; i < 4; ++i) {
      int ra = (wm + i*16 + l15)*32 + kq;
      fah[i] = *(const bf16x8*)&sAh[ra];
      fal[i] = *(const bf16x8*)&sAl[ra];
      int rb = (wn + i*16 + l15)*32 + kq;
      fbh[i] = *(const bf16x8*)&sBh[rb];
      fbl[i] = *(const bf16x8*)&sBl[rb];
    }
    #pragma unroll
    for (int i = 0; i < 4; ++i)
      #pragma unroll
      for (int j = 0; j < 4; ++j) {
        acc[i][j] = __builtin_amdgcn_mfma_f32_16x16x32_bf16(fah[i], fbl[j], acc[i][j], 0, 0, 0);
        acc[i][j] = __builtin_amdgcn_mfma_f32_16x16x32_bf16(fal[i], fbh[j], acc[i][j], 0, 0, 0);
        acc[i][j] = __builtin_amdgcn_mfma_f32_16x16x32_bf16(fah[i], fbh[j], acc[i][j], 0, 0, 0);
      }
  }
  #pragma unroll
  for (int i = 0; i < 4; ++i) {
    #pragma unroll
    for (int j = 0; j < 4; ++j) {
      int col = n0 + wn + j*16 + l15;
      if (col >= N) continue;
      float bv = bias[col];
      #pragma unroll
      for (int r = 0; r < 4; ++r) {
        int row = m0 + wm + i*16 + quad*4 + r;
        C[(size_t)row*N + col] = acc[i][j][r] + bv;
      }
    }
  }
}

// ---------- 3. per-row L2 normalize -> 3 bf16 planes, PADDED [.][KP2] ----------
__global__ __launch_bounds__(256) void rownorm_k(const float* __restrict__ xp,
                          unsigned short* __restrict__ y0, unsigned short* __restrict__ y1,
                          unsigned short* __restrict__ y2) {
  int lane = threadIdx.x & 63;
  int n = blockIdx.x*4 + (threadIdx.x >> 6);
  const float* r = xp + (size_t)n*EC;
  float ss = 0.f;
  for (int e = lane; e < EC; e += 64) { float v = r[e]; ss += v*v; }
  #pragma unroll
  for (int off = 32; off > 0; off >>= 1) ss += __shfl_down(ss, off);
  float nrm = sqrtf(__shfl(ss, 0));
  float s = 1.f / fmaxf(nrm, 1e-12f);
  for (int e = lane; e < KP2; e += 64) {
    unsigned short a = 0, b = 0, c = 0;
    if (e < EC) { float v = r[e]*s; split3_(v, a, b, c); }
    y0[(size_t)n*KP2 + e] = a;
    y1[(size_t)n*KP2 + e] = b;
    y2[(size_t)n*KP2 + e] = c;
  }
}

// ---------- 5. per-token head attention, 4 tokens/block (1 wave per token) ----------
__global__ __launch_bounds__(256) void attn_k(const float* __restrict__ qkv, float* __restrict__ outS,
                      float* __restrict__ imp) {
  __shared__ float row[4][E3];
  __shared__ float sc[4][36];
  __shared__ int sel[4][6];
  int t = threadIdx.x;
  int w = t >> 6, lane = t & 63;
  int n = blockIdx.x*4 + w;
  const float4* src = (const float4*)(qkv + (size_t)n * E3);
  float4* drow = (float4*)row[w];
  for (int i = lane; i < 252; i += 64) drow[i] = src[i];
  __syncthreads();
  if (lane < 36) {
    int h = lane / 6, g = lane % 6;
    const float* q = row[w] + h*HDC;
    const float* kk = row[w] + EC + g*HDC;
    float s = 0.f;
    #pragma unroll
    for (int d = 0; d < HDC; ++d) s += q[d]*kk[d];
    sc[w][lane] = s;
  }
  __syncthreads();
  if (lane < 6) {
    float best = sc[w][lane*6]; int bi = 0;
    #pragma unroll
    for (int g = 1; g < 6; ++g) { float vv = sc[w][lane*6+g]; if (vv > best) { best = vv; bi = g; } }
    sel[w][lane] = bi;
  }
  __syncthreads();
  float ss = 0.f;
  for (int e = lane; e < EC; e += 64) {
    int d = e / 6, h = e - d*6;       // channel c = d*HEADS + h
    float vv = row[w][2*EC + sel[w][h]*HDC + d];
    outS[(size_t)n*EC + e] = vv;
    ss += vv*vv;
  }
  #pragma unroll
  for (int off = 32; off > 0; off >>= 1) ss += __shfl_down(ss, off);
  if (lane == 0) imp[n] = sqrtf(ss);
}

// ---------- 6. top-819 of 4096 per batch: exact radix-select + 1024-bitonic ----------
__global__ __launch_bounds__(1024) void topk_k(const float* __restrict__ imp, int* __restrict__ idxb,
                       int* __restrict__ map) {
  __shared__ unsigned hist[257];
  __shared__ unsigned selNeed, selPrefix, cnt;
  __shared__ unsigned cv[1024];
  __shared__ int ci[1024];
  int b = blockIdx.x, t = threadIdx.x;
  unsigned key[4];
  #pragma unroll
  for (int j = 0; j < 4; ++j) key[j] = __float_as_uint(imp[b*4096 + j*1024 + t]);
  #pragma unroll
  for (int j = 0; j < 4; ++j) map[b*4096 + j*1024 + t] = -1;   // init; re-written below for selected
  if (t == 0) { selNeed = KC; selPrefix = 0u; cnt = 0u; }
  __syncthreads();
  // 4 MSB-first passes; invariant: current class (prefix) holds >= selNeed keys
  for (int pass = 0; pass < 4; ++pass) {
    int sh = 24 - pass*8;
    if (t < 257) hist[t] = 0u;
    __syncthreads();
    unsigned pfx = selPrefix;
    #pragma unroll
    for (int j = 0; j < 4; ++j) {
      unsigned k = key[j];
      bool in = (pass == 0) || ((k >> (sh + 8)) == pfx);
      if (in) atomicAdd(&hist[(k >> sh) & 0xFFu], 1u);
    }
    __syncthreads();
    // parallel suffix sum: hist[i] := count(digit >= i)
    for (int off = 1; off < 256; off <<= 1) {
      unsigned v2 = 0u;
      if (t < 256 && t + off < 256) v2 = hist[t + off];
      __syncthreads();
      if (t < 256) hist[t] += v2;
      __syncthreads();
    }
    unsigned need = selNeed;
    __syncthreads();
    if (t < 256) {
      unsigned c0 = hist[t];
      unsigned c1 = (t < 255) ? hist[t+1] : 0u;
      if (c0 >= need && c1 < need) {       // unique crossing bin
        selNeed = need - c1;
        selPrefix = (pfx << 8) | (unsigned)t;
      }
    }
    __syncthreads();
  }
  unsigned K819 = selPrefix;               // exact KC-th largest key
  // gather all keys >= K819 (~KC of them; ties resolved by the sort below)
  #pragma unroll
  for (int j = 0; j < 4; ++j) {
    if (key[j] >= K819) {
      unsigned pos = atomicAdd(&cnt, 1u);
      if (pos < 1024u) { cv[pos] = key[j]; ci[pos] = j*1024 + t; }
    }
  }
  __syncthreads();
  unsigned total = cnt < 1024u ? cnt : 1024u;
  if ((unsigned)t >= total) { cv[t] = 0u; ci[t] = 0x7FFFFFFF; }
  __syncthreads();
  // bitonic sort 1024 by (value desc, index asc)
  for (int k = 2; k <= 1024; k <<= 1) {
    for (int j = k >> 1; j > 0; j >>= 1) {
      int p = t ^ j;
      if (p > t) {
        unsigned va = cv[t], vb = cv[p];
        int ia = ci[t], ib = ci[p];
        bool aFirst = (va > vb) || (va == vb && ia < ib);
        bool up = ((t & k) == 0);
        if (up ? !aFirst : aFirst) { cv[t] = vb; cv[p] = va; ci[t] = ib; ci[p] = ia; }
      }
      __syncthreads();
    }
  }
  if (t < KC) {
    int l = ci[t];
    idxb[b*KC + t] = l;
    map[b*4096 + l] = t;
  }
}

// ---------- 7a+7b fused: per-channel composed kernel K2[e][0..TRUNC) ----------
__global__ __launch_bounds__(256) void ssmk_k(const float* __restrict__ A, const float* __restrict__ Bp,
                      const float* __restrict__ Cp, const float* __restrict__ convw,
                      float* __restrict__ K2) {
  __shared__ float Ab[256], Pb[256], Tb[256];
  __shared__ float V[TRUNC][16];
  __shared__ float K1[TRUNC];
  int e = blockIdx.x, t = threadIdx.x;
  int r = t >> 4, c = t & 15;
  Ab[t] = A[t];
  __syncthreads();
  float x;
  x = 0.f;
  #pragma unroll
  for (int k = 0; k < 16; ++k) x += Ab[r*16+k]*Ab[k*16+c];
  Pb[t] = x; __syncthreads();                 // A^2
  x = 0.f;
  #pragma unroll
  for (int k = 0; k < 16; ++k) x += Pb[r*16+k]*Pb[k*16+c];
  Tb[t] = x; __syncthreads();                 // A^4
  x = 0.f;
  #pragma unroll
  for (int k = 0; k < 16; ++k) x += Tb[r*16+k]*Tb[k*16+c];
  Pb[t] = x; __syncthreads();                 // A^8
  x = 0.f;
  #pragma unroll
  for (int k = 0; k < 16; ++k) x += Pb[r*16+k]*Pb[k*16+c];
  Tb[t] = x; __syncthreads();                 // A^16
  if (t < 16) V[0][t] = sigmoidf_(Bp[t]);
  __syncthreads();
  for (int j = 1; j < 16; ++j) {
    if (t < 16) {
      float s = 0.f;
      #pragma unroll
      for (int k = 0; k < 16; ++k) s += Ab[t*16+k]*V[j-1][k];
      V[j][t] = s;
    }
    __syncthreads();
  }
  for (int sg = 1; sg < TRUNC/16; ++sg) {     // V[16sg+g] = A^16 V[16(sg-1)+g]
    int g = t >> 4, rr = t & 15;
    float s = 0.f;
    #pragma unroll
    for (int k = 0; k < 16; ++k) s += Tb[rr*16+k]*V[16*(sg-1)+g][k];
    V[16*sg+g][rr] = s;
    __syncthreads();
  }
  float sC[16];
  #pragma unroll
  for (int s = 0; s < 16; ++s) sC[s] = sigmoidf_(Cp[e*16+s]);
  for (int i = t; i < TRUNC; i += 256) {
    float s = 0.f;
    #pragma unroll
    for (int k = 0; k < 16; ++k) s += sC[k]*V[i][k];
    K1[i] = s;
  }
  __syncthreads();
  float w0 = convw[e*4+0], w1 = convw[e*4+1], w2 = convw[e*4+2], w3 = convw[e*4+3];
  for (int m = t; m < TRUNC; m += 256) {
    float acc = w3*K1[m];
    if (m >= 1) acc += w2*K1[m-1];
    if (m >= 2) acc += w1*K1[m-2];
    if (m >= 3) acc += w0*K1[m-3];
    K2[(size_t)e*TRUNC + m] = acc;
  }
}

// ---------- 7c. fused gather+conv+scan (TRUNC taps) -> Yt fp32 [e][b*KCP+tt] ----------
#define XSZ (TRUNC + KC + 8)
#define XSWZ (XSZ + XSZ/32 + 2)
__device__ __forceinline__ int swz_(int i){ return i + (i>>5); }
__global__ __launch_bounds__(128) void ssmconv_k(const float* __restrict__ outS, const int* __restrict__ idxb,
                         const float* __restrict__ K2, float* __restrict__ Yt) {
  __shared__ float X[XSWZ];
  __shared__ float Ks[TRUNC];
  int bid = blockIdx.x;
  int b = bid & 7, e = bid >> 3, t = threadIdx.x;
  for (int i = t; i < XSWZ; i += 128) X[i] = 0.f;
  __syncthreads();
  for (int i = t; i < KC; i += 128) {
    int l = idxb[b*KC + i];
    X[swz_(TRUNC + i)] = outS[((size_t)(b*LL + l))*EC + e];
  }
  for (int i = t; i < TRUNC; i += 128) Ks[i] = K2[(size_t)e*TRUNC + i];
  __syncthreads();
  int t0 = t*8;
  if (t0 < KC) {
    int base = TRUNC + t0;
    float a0=0,a1=0,a2=0,a3=0,a4=0,a5=0,a6=0,a7=0;
    float r0=X[swz_(base+0)], r1=X[swz_(base+1)], r2=X[swz_(base+2)], r3=X[swz_(base+3)];
    float r4=X[swz_(base+4)], r5=X[swz_(base+5)], r6=X[swz_(base+6)], r7=X[swz_(base+7)];
    #pragma unroll 4
    for (int m = 0; m < TRUNC; m += 8) {
      float4 k0 = *(const float4*)&Ks[m];
      float4 k1 = *(const float4*)&Ks[m+4];
      float kv;
      kv = k0.x;
      a0+=kv*r0; a1+=kv*r1; a2+=kv*r2; a3+=kv*r3; a4+=kv*r4; a5+=kv*r5; a6+=kv*r6; a7+=kv*r7;
      r7=r6; r6=r5; r5=r4; r4=r3; r3=r2; r2=r1; r1=r0; r0=X[swz_(base-m-1)];
      kv = k0.y;
      a0+=kv*r0; a1+=kv*r1; a2+=kv*r2; a3+=kv*r3; a4+=kv*r4; a5+=kv*r5; a6+=kv*r6; a7+=kv*r7;
      r7=r6; r6=r5; r5=r4; r4=r3; r3=r2; r2=r1; r1=r0; r0=X[swz_(base-m-2)];
      kv = k0.z;
      a0+=kv*r0; a1+=kv*r1; a2+=kv*r2; a3+=kv*r3; a4+=kv*r4; a5+=kv*r5; a6+=kv*r6; a7+=kv*r7;
      r7=r6; r6=r5; r5=r4; r4=r3; r3=r2; r2=r1; r1=r0; r0=X[swz_(base-m-3)];
      kv = k0.w;
      a0+=kv*r0; a1+=kv*r1; a2+=kv*r2; a3+=kv*r3; a4+=kv*r4; a5+=kv*r5; a6+=kv*r6; a7+=kv*r7;
      r7=r6; r6=r5; r5=r4; r4=r3; r3=r2; r2=r1; r1=r0; r0=X[swz_(base-m-4)];
      kv = k1.x;
      a0+=kv*r0; a1+=kv*r1; a2+=kv*r2; a3+=kv*r3; a4+=kv*r4; a5+=kv*r5; a6+=kv*r6; a7+=kv*r7;
      r7=r6; r6=r5; r5=r4; r4=r3; r3=r2; r2=r1; r1=r0; r0=X[swz_(base-m-5)];
      kv = k1.y;
      a0+=kv*r0; a1+=kv*r1; a2+=kv*r2; a3+=kv*r3; a4+=kv*r4; a5+=kv*r5; a6+=kv*r6; a7+=kv*r7;
      r7=r6; r6=r5; r5=r4; r4=r3; r3=r2; r2=r1; r1=r0; r0=X[swz_(base-m-6)];
      kv = k1.z;
      a0+=kv*r0; a1+=kv*r1; a2+=kv*r2; a3+=kv*r3; a4+=kv*r4; a5+=kv*r5; a6+=kv*r6; a7+=kv*r7;
      r7=r6; r6=r5; r5=r4; r4=r3; r3=r2; r2=r1; r1=r0; r0=X[swz_(base-m-7)];
      kv = k1.w;
      a0+=kv*r0; a1+=kv*r1; a2+=kv*r2; a3+=kv*r3; a4+=kv*r4; a5+=kv*r5; a6+=kv*r6; a7+=kv*r7;
      r7=r6; r6=r5; r5=r4; r4=r3; r3=r2; r2=r1; r1=r0; r0=X[swz_(base-m-8)];
    }
    float acc[8] = {a0,a1,a2,a3,a4,a5,a6,a7};
    float* dst = Yt + (size_t)e*YTS + b*KCP + t0;
    #pragma unroll
    for (int i = 0; i < 8; ++i) {
      if (t0 + i < KC) dst[i] = acc[i];     // contiguous per-thread run: coalesced
    }
  }
}

// ---------- 7d. transpose + split: Yt [336][YTS] fp32 -> ysh/ysl PADDED [YTS][KP2] bf16 ----------
__global__ __launch_bounds__(256) void tsplit_k(const float* __restrict__ Yt,
                         unsigned short* __restrict__ ysh, unsigned short* __restrict__ ysl) {
  __shared__ float T[32][33];
  int tb = blockIdx.x;          // token tile: 0..25 (26*32 = 832 = KCP)
  int eb = blockIdx.y;          // channel tile: 0..10 (11*32 = 352 = KP2)
  int b  = blockIdx.z;
  int tx = threadIdx.x & 31, ty = threadIdx.x >> 5;   // 32 x 8
  int t0 = tb*32, e0 = eb*32;
  #pragma unroll
  for (int j = 0; j < 4; ++j) {
    int e = e0 + ty + j*8;
    T[ty + j*8][tx] = (e < EC) ? Yt[(size_t)e*YTS + b*KCP + t0 + tx] : 0.f;
  }
  __syncthreads();
  #pragma unroll
  for (int j = 0; j < 4; ++j) {
    int tt = t0 + ty + j*8;
    int e  = e0 + tx;
    float v = (tt < KC && e < EC) ? T[tx][ty + j*8] : 0.f;
    unsigned short h = bf16rn_(v);
    size_t off = ((size_t)(b*KCP + tt))*KP2 + e;
    ysh[off] = h;
    ysl[off] = bf16rn_(v - bf2f_(h));
  }
}

// ---------- 9. epilogue: out = x + scatter(xproc by map) ----------
__global__ __launch_bounds__(256) void epi_k(const float* __restrict__ x, const float* __restrict__ xproc,
                      const int* __restrict__ map, float* __restrict__ out) {
  size_t i = (size_t)blockIdx.x*256 + threadIdx.x;  // float4 index over 4194304
  int row = (int)(i >> 7);
  int c = ((int)i & 127) << 2;
  int b = row >> 12;
  float4 v = ((const float4*)x)[i];
  int m = map[row];
  if (m >= 0) {
    const float4 pv = *(const float4*)(xproc + ((size_t)(b*KCP + m))*DIMC + c);
    v.x += pv.x; v.y += pv.y; v.z += pv.z; v.w += pv.w;
  }
  ((float4*)out)[i] = v;
}

extern "C" void kernel_launch(void* const* d_in, const int* in_sizes, int n_in,
                              void* d_out, int out_size, void* d_ws, size_t ws_size,
                              hipStream_t stream) {
  const float* x     = (const float*)d_in[0];
  const float* alpha = (const float*)d_in[1];
  const float* dyt_w = (const float*)d_in[2];
  const float* dyt_b = (const float*)d_in[3];
  const float* W_in  = (const float*)d_in[4];
  const float* b_in  = (const float*)d_in[5];
  const float* W_qkv = (const float*)d_in[6];
  const float* b_qkv = (const float*)d_in[7];
  const float* convw = (const float*)d_in[8];
  const float* A     = (const float*)d_in[9];
  const float* Bp    = (const float*)d_in[10];
  const float* Cp    = (const float*)d_in[11];
  const float* W_out = (const float*)d_in[12];
  const float* b_out = (const float*)d_in[13];

  float* outF = (float*)d_out;          // scratch: attn-out (32768x336), then final output

  float* ws = (float*)d_ws;
  // ---- full-batch layout (~218 MB) ----
  unsigned short* xn0  = (unsigned short*)(ws + 0);          // NN*512 bf16 = 8,388,608 f
  unsigned short* xn1  = (unsigned short*)(ws + 8388608);
  unsigned short* xn2  = (unsigned short*)(ws + 16777216);
  float*          xp   = ws + 25165824;                      // NN*336 = 11,010,048 f
  float*          qkv  = ws + 0;                             // NN*1008 = 33,030,144 f (overlays xn+xp)
  // persistent (padded planes):
  unsigned short* xpn0 = (unsigned short*)(ws + 36175872);   // NN*KP2 bf16 = 5,767,168 f each
  unsigned short* xpn1 = (unsigned short*)(ws + 41943040);
  unsigned short* xpn2 = (unsigned short*)(ws + 47710208);
  float*          imp  = ws + 53477376;                      // 32768 f
  int*            idxb = (int*)(ws + 53510144);              // 8192 slots
  int*            mapb = (int*)(ws + 53518336);              // 32768
  unsigned short* wi0  = (unsigned short*)(ws + 53551104);   // NP1*512 bf16 = 98,304 f each
  unsigned short* wi1  = (unsigned short*)(ws + 53649408);
  unsigned short* wi2  = (unsigned short*)(ws + 53747712);
  unsigned short* wq0  = (unsigned short*)(ws + 53846016);   // NP2*KP2 bf16 = 180,224 f each
  unsigned short* wq1  = (unsigned short*)(ws + 54026240);
  unsigned short* wq2  = (unsigned short*)(ws + 54206464);
  unsigned short* woh  = (unsigned short*)(ws + 54386688);   // 512*KP2 bf16 = 90,112 f each
  unsigned short* wol  = (unsigned short*)(ws + 54476800);   // end 54,566,912 f = 218.3 MB
  // overlays on R0 after attn_k (qkv dead):
  float*          K2    = ws + 0;                            // 336*160 = 53,760 f
  unsigned short* ysh   = (unsigned short*)(ws + 53760);     // YTS*KP2 bf16 = 1,171,456 f each
  unsigned short* ysl   = (unsigned short*)(ws + 1225216);
  float*          Yt    = ws + 2396672;                      // 336*YTS = 2,236,416 f
  float*          xproc = ws + 4633088;                      // YTS*512 = 3,407,872 f (end 8,040,960)

  // 0. transpose+split weights (padded planes)
  prepw3x2_k<<<(NP1*DIMC + NP2*KP2 + 255)/256, 256, 0, stream>>>(W_in, wi0, wi1, wi2,
                                                                 W_qkv, wq0, wq1, wq2);
  prepwo_k<<<(DIMC*KP2 + 255)/256, 256, 0, stream>>>(W_out, woh, wol);

  // 1-5 full batch, single dispatches
  dyt_k<<<NN*DIMC/1024, 256, 0, stream>>>(x, xn0, xn1, xn2, alpha, dyt_w, dyt_b);
  mgemm6_k<<<dim3(NP1/128, NN/128), 256, 0, stream>>>(xn0, xn1, xn2, wi0, wi1, wi2, b_in, xp, EC, DIMC);
  rownorm_k<<<NN/4, 256, 0, stream>>>(xp, xpn0, xpn1, xpn2);
  mgemm6_k<<<dim3(NP2/128, NN/128), 256, 0, stream>>>(xpn0, xpn1, xpn2, wq0, wq1, wq2, b_qkv, qkv, E3, KP2);
  attn_k<<<NN/4, 256, 0, stream>>>(qkv, outF, imp);

  // 6. top-k per batch (radix select + small sort)
  topk_k<<<BB, 1024, 0, stream>>>(imp, idxb, mapb);
  // 7. composed SSM kernel + fused conv
  ssmk_k<<<EC, 256, 0, stream>>>(A, Bp, Cp, convw, K2);
  ssmconv_k<<<EC*BB, 128, 0, stream>>>(outF, idxb, K2, Yt);
  // 7d. transpose+split Yt -> padded ysh/ysl [token][channel]
  tsplit_k<<<dim3(KCP/32, KP2/32, BB), 256, 0, stream>>>(Yt, ysh, ysl);
  // 9. xproc = ys @ W_out + b_out (gload_lds bf16x3 MFMA, padded M=6656/K=352)
  mgemm3_k<<<dim3(4, YTS/128), 256, 0, stream>>>(ysh, ysl, woh, wol, b_out, xproc, DIMC, KP2);
  // 10. output = x + scatter(xproc)
  epi_k<<<16384, 256, 0, stream>>>(x, xproc, mapb, outF);
}